// Round 5
// baseline (975.882 us; speedup 1.0000x reference)
//
#include <hip/hip_runtime.h>
#include <math.h>

// ---------------- dims ----------------
// T=S=48, H=250, EMB=300, gates=1000, 13 sim planes, convnet 48->24->12->6->3->1

typedef __attribute__((ext_vector_type(2))) _Float16 h2f;

// workspace layout (floats)
#define OFF_XW    0            // 4*48*1000 = 192000 (bias pre-folded)
#define OFF_HS    192000       // 4*48*250  = 48000
#define OFF_SC    240000       // 13*2304 = 29952
#define OFF_BUFA  269952       // 73728 (conv1 out 128x24x24; conv3 out; conv5 out)
#define OFF_BUFB  343680       // 23616 (conv2 out 164x12x12; conv4 out)
#define OFF_WIHT  367296       // 600000 fp32 transposed w_ih [2][300][1000]
#define OFF_SEL   967296       // 2*2304 bytes = 1152 floats
// total ~968448 floats (~3.9 MB)

__device__ __forceinline__ float sigf(float x) { return 1.f / (1.f + expf(-x)); }

#if __has_builtin(__builtin_amdgcn_fdot2)
__device__ __forceinline__ float dot2(h2f a, h2f b, float c) {
    return __builtin_amdgcn_fdot2(a, b, c, false);
}
#else
__device__ __forceinline__ float dot2(h2f a, h2f b, float c) {
    return c + (float)a.x * (float)b.x + (float)a.y * (float)b.y;
}
#endif

// ---------------- 0) tiled transpose w_ih: [1000][300] -> [300][1000] ----------------
// grid dim3(32, 10, 2), block dim3(32, 32)
__global__ void transpose_wih_kernel(const float* __restrict__ wf, const float* __restrict__ wb,
                                     float* __restrict__ wT)
{
    __shared__ float tile[32][33];
    int dir = blockIdx.z;
    const float* w = dir ? wb : wf;

    int j = blockIdx.x * 32 + threadIdx.y;   // row of w (0..999)
    int k = blockIdx.y * 32 + threadIdx.x;   // col of w (0..299)
    if (j < 1000 && k < 300)
        tile[threadIdx.y][threadIdx.x] = w[(size_t)j * 300 + k];
    __syncthreads();

    int ko = blockIdx.y * 32 + threadIdx.y;
    int jo = blockIdx.x * 32 + threadIdx.x;
    if (ko < 300 && jo < 1000)
        wT[(size_t)dir * 300000 + (size_t)ko * 1000 + jo] = tile[threadIdx.x][threadIdx.y];
}

// ---------------- 1) embedding gather + x @ w_ih^T + bias (coalesced via wT) ----------------
__global__ void embed_xw_kernel(const int* __restrict__ x1, const int* __restrict__ x2,
                                const float* __restrict__ emb, const float* __restrict__ wT,
                                const float* __restrict__ b_f, const float* __restrict__ b_b,
                                float* __restrict__ xW)
{
    int t = blockIdx.x % 48;
    int m = blockIdx.x / 48;
    const int* x = (m < 2) ? x1 : x2;
    const float* w = wT + (size_t)(m & 1) * 300000;
    const float* bias = (m & 1) ? b_b : b_f;

    __shared__ float e[300];
    int row = x[t];
    for (int k = threadIdx.x; k < 300; k += 512)
        e[k] = emb[(size_t)row * 300 + k];
    __syncthreads();

    int j0 = threadIdx.x;
    int j1 = threadIdx.x + 512;
    int j1c = j1 < 1000 ? j1 : 999;
    float a0 = 0.f, a1 = 0.f;
    #pragma unroll 4
    for (int k = 0; k < 300; ++k) {
        float ek = e[k];
        const float* wr = w + (size_t)k * 1000;
        a0 += ek * wr[j0];
        a1 += ek * wr[j1c];
    }
    float* out = xW + ((size_t)m * 48 + t) * 1000;
    out[j0] = a0 + bias[j0];
    if (j1 < 1000) out[j1] = a1 + bias[j1];
}

// ---------------- 2) LSTM: ONE block per (seq,dir); thread t owns unit t (all 4 gates) ----------------
// No cross-block sync. Weights register-resident fp16 pairs; h via parity-double-buffered LDS.
__global__ void __launch_bounds__(256, 1) lstm_kernel(
    const float* __restrict__ xW,
    const float* __restrict__ w_hh_f, const float* __restrict__ w_hh_b,
    float* __restrict__ hs)
{
    int m   = blockIdx.x;           // 0: s1 fwd, 1: s1 bwd, 2: s2 fwd, 3: s2 bwd
    int dir = m & 1;
    const float* w  = dir ? w_hh_b : w_hh_f;
    const float* xw = xW + (size_t)m * 48000;
    float* out      = hs + (size_t)m * 12000;

    int t = threadIdx.x;
    bool active = t < 250;

    __shared__ __align__(16) unsigned int hp[2][128];   // packed fp16 h pairs

    // 4 gate rows (unit t) -> registers as packed fp16 pairs
    h2f wreg[4][125];
    if (active) {
        #pragma unroll
        for (int g = 0; g < 4; ++g) {
            const float* r = w + (size_t)(g * 250 + t) * 250;
            #pragma unroll
            for (int j = 0; j < 125; ++j) {
                float2 v = *(const float2*)(r + 2 * j);
                h2f pv; pv.x = (_Float16)v.x; pv.y = (_Float16)v.y;
                wreg[g][j] = pv;
            }
        }
    }
    if (t < 128) { hp[0][t] = 0u; hp[1][t] = 0u; }
    float c = 0.f;
    __syncthreads();

    for (int step = 0; step < 48; ++step) {
        int tt  = dir ? 47 - step : step;
        int par = step & 1;
        if (active) {
            const float* xwt = xw + tt * 1000;
            float acc[4];
            acc[0] = xwt[t];
            acc[1] = xwt[250 + t];
            acc[2] = xwt[500 + t];
            acc[3] = xwt[750 + t];
            const uint4* hp4 = (const uint4*)hp[par];
            #pragma unroll
            for (int jj = 0; jj < 31; ++jj) {
                uint4 q = hp4[jj];
                h2f h0 = *(h2f*)&q.x, h1 = *(h2f*)&q.y, h2v = *(h2f*)&q.z, h3 = *(h2f*)&q.w;
                #pragma unroll
                for (int g = 0; g < 4; ++g) {
                    acc[g] = dot2(wreg[g][4 * jj + 0], h0, acc[g]);
                    acc[g] = dot2(wreg[g][4 * jj + 1], h1, acc[g]);
                    acc[g] = dot2(wreg[g][4 * jj + 2], h2v, acc[g]);
                    acc[g] = dot2(wreg[g][4 * jj + 3], h3, acc[g]);
                }
            }
            {
                unsigned int q = hp[par][124];
                h2f hv = *(h2f*)&q;
                #pragma unroll
                for (int g = 0; g < 4; ++g)
                    acc[g] = dot2(wreg[g][124], hv, acc[g]);
            }
            float iv = sigf(acc[0]);
            float fv = sigf(acc[1]);
            float gv = tanhf(acc[2]);
            float ov = sigf(acc[3]);
            c = fv * c + iv * gv;
            float hn = ov * tanhf(c);
            out[tt * 250 + t] = hn;
            float hi = __shfl_down(hn, 1);
            if (!(t & 1)) {
                h2f pv; pv.x = (_Float16)hn; pv.y = (_Float16)hi;
                hp[par ^ 1][t >> 1] = *(unsigned int*)&pv;
            }
        }
        __syncthreads();
    }
}

// ---------------- 3) similarity cube with inline norms: 13 x 48 x 48 ----------------
__global__ void sim_kernel(const float* __restrict__ hs, float* __restrict__ sc)
{
    int p = blockIdx.x;
    int i = p / 48, jj = p % 48;
    const float* h1f = hs + ((size_t)0 * 48 + i) * 250;
    const float* h1b = hs + ((size_t)1 * 48 + i) * 250;
    const float* h2f = hs + ((size_t)2 * 48 + jj) * 250;
    const float* h2b = hs + ((size_t)3 * 48 + jj) * 250;
    int lane = threadIdx.x;
    float dff = 0.f, dbb = 0.f, dfb = 0.f, dbf = 0.f;
    float sfa = 0.f, sba = 0.f, caa = 0.f;
    float sfb = 0.f, sbb = 0.f, cbb = 0.f;
    for (int k = lane; k < 250; k += 64) {
        float af = h1f[k], ab = h1b[k], bf = h2f[k], bb = h2b[k];
        dff += af * bf; dbb += ab * bb; dfb += af * bb; dbf += ab * bf;
        sfa += af * af; sba += ab * ab; caa += af * ab;
        sfb += bf * bf; sbb += bb * bb; cbb += bf * bb;
    }
    #pragma unroll
    for (int o = 32; o; o >>= 1) {
        dff += __shfl_down(dff, o); dbb += __shfl_down(dbb, o);
        dfb += __shfl_down(dfb, o); dbf += __shfl_down(dbf, o);
        sfa += __shfl_down(sfa, o); sba += __shfl_down(sba, o);
        caa += __shfl_down(caa, o);
        sfb += __shfl_down(sfb, o); sbb += __shfl_down(sbb, o);
        cbb += __shfl_down(cbb, o);
    }
    if (lane == 0) {
        #define EMIT(basep, dotv, sa2, sb2)                                 \
        {                                                                   \
            float na = sqrtf(sa2), nbv = sqrtf(sb2);                        \
            float dv = (dotv);                                              \
            sc[(basep) * 2304 + p] = dv;                                    \
            sc[((basep) + 1) * 2304 + p] = dv / (na * nbv + 1e-8f);         \
            float d2 = fmaxf(na * na + nbv * nbv - 2.f * dv, 1e-12f);       \
            sc[((basep) + 2) * 2304 + p] = sqrtf(d2);                       \
        }
        EMIT(0, dff + dbb, sfa + sba, sfb + sbb);
        EMIT(3, dff, sfa, sfb);
        EMIT(6, dbb, sba, sbb);
        EMIT(9, dff + dfb + dbf + dbb, sfa + sba + 2.f * caa, sfb + sbb + 2.f * cbb);
        #undef EMIT
        // plane 12 is identically zero and skipped by conv1
    }
}

// ---------------- 4) greedy top-k: 2 blocks (one per plane), single wave each ----------------
__global__ void greedy_kernel(const float* __restrict__ sc, unsigned char* __restrict__ sel)
{
    __shared__ float vals[2304];
    __shared__ int s1[48], s2[48];
    __shared__ unsigned char selL[2304];
    int lane = threadIdx.x;
    int plane = 10 + blockIdx.x;

    for (int q = 0; q < 36; ++q) {
        int i = lane + 64 * q;
        vals[i] = sc[plane * 2304 + i];
        selL[i] = 0;
    }
    if (lane < 48) { s1[lane] = 0; s2[lane] = 0; }
    __syncthreads();

    float lv = -INFINITY; int li = 0x7fffffff;
    for (int q = 0; q < 36; ++q) {
        int i = lane + 64 * q;
        float v = vals[i];
        if (v > lv) { lv = v; li = i; }
    }

    for (int it = 0; it < 96; ++it) {
        float bv = lv; int bi = li;
        #pragma unroll
        for (int o = 1; o < 64; o <<= 1) {
            float ov = __shfl_xor(bv, o);
            int   oi = __shfl_xor(bi, o);
            if (ov > bv || (ov == bv && oi < bi)) { bv = ov; bi = oi; }
        }
        if (lane == (bi & 63)) {
            vals[bi] = -INFINITY;
            lv = -INFINITY; li = 0x7fffffff;
            for (int q = 0; q < 36; ++q) {
                int i = lane + 64 * q;
                float v = vals[i];
                if (v > lv) { lv = v; li = i; }
            }
        }
        if (lane == 0) {
            int p1 = bi / 48, p2 = bi % 48;
            if (s1[p1] + s2[p2] == 0) { s1[p1] = 1; s2[p2] = 1; selL[bi] = 1; }
        }
    }
    __syncthreads();
    for (int q = 0; q < 36; ++q) {
        int i = lane + 64 * q;
        sel[blockIdx.x * 2304 + i] = selL[i];
    }
}

// ---------------- 5) conv1 (12 planes ->128, 48x48) + fused focus mask + relu + pool2x2 ----------------
// grid 128*9, block 256 (16x16 tile)
__global__ void conv1_pool_kernel(const float* __restrict__ sc, const unsigned char* __restrict__ sel,
                                  const float* __restrict__ w, const float* __restrict__ bias,
                                  float* __restrict__ out)
{
    __shared__ float tile[256];
    int co  = blockIdx.x / 9;
    int tl  = blockIdx.x % 9;
    int ty0 = (tl / 3) * 16, tx0 = (tl % 3) * 16;
    int tx = threadIdx.x % 16, ty = threadIdx.x / 16;
    int x = tx0 + tx, y = ty0 + ty;

    float mv[9];
    #pragma unroll
    for (int ky = 0; ky < 3; ++ky) {
        int iy = y + ky - 1;
        #pragma unroll
        for (int kx = 0; kx < 3; ++kx) {
            int ix = x + kx - 1;
            float mm = 0.f;
            if (iy >= 0 && iy < 48 && ix >= 0 && ix < 48) {
                int p = iy * 48 + ix;
                mm = (sel[p] | sel[2304 + p]) ? 1.0f : 0.1f;
            }
            mv[ky * 3 + kx] = mm;
        }
    }

    float acc = bias[co];
    const float* wco = w + (size_t)co * 13 * 9;
    for (int ci = 0; ci < 12; ++ci) {
        const float* inp = sc + (size_t)ci * 2304;
        const float* wp = wco + ci * 9;
        #pragma unroll
        for (int ky = 0; ky < 3; ++ky) {
            int iy = y + ky - 1;
            if (iy < 0 || iy >= 48) continue;
            #pragma unroll
            for (int kx = 0; kx < 3; ++kx) {
                int ix = x + kx - 1;
                if (ix < 0 || ix >= 48) continue;
                acc += inp[iy * 48 + ix] * mv[ky * 3 + kx] * wp[ky * 3 + kx];
            }
        }
    }
    tile[threadIdx.x] = acc > 0.f ? acc : 0.f;
    __syncthreads();
    if (threadIdx.x < 64) {
        int py = threadIdx.x / 8, px = threadIdx.x % 8;
        float a = tile[(py * 2) * 16 + px * 2];
        float b = tile[(py * 2) * 16 + px * 2 + 1];
        float cc = tile[(py * 2 + 1) * 16 + px * 2];
        float d = tile[(py * 2 + 1) * 16 + px * 2 + 1];
        float best = fmaxf(fmaxf(a, b), fmaxf(cc, d));
        out[(size_t)co * 576 + (ty0 / 2 + py) * 24 + (tx0 / 2 + px)] = best;
    }
}

// ---------------- 6) Cin-split conv3x3 + relu + pool ----------------
// grid (Cout, tilesY, tilesX); block = P*CC threads, P = tileH*tileW
__global__ void conv_cs_kernel(const float* __restrict__ in, const float* __restrict__ w,
                               const float* __restrict__ bias, float* __restrict__ out,
                               int Cin, int H, int W, int tileH, int tileW,
                               int cpc, int CC, int pk, int ps, int PHf, int PWf)
{
    extern __shared__ float sm[];          // P*CC partials + P results
    int P = tileH * tileW;
    int co = blockIdx.x;
    int ty0 = blockIdx.y * tileH, tx0 = blockIdx.z * tileW;
    int t = threadIdx.x;
    int pix = t % P, chunk = t / P;
    int y = ty0 + pix / tileW, x = tx0 + pix % tileW;
    int c0 = chunk * cpc;
    int c1 = c0 + cpc; if (c1 > Cin) c1 = Cin;

    float acc = 0.f;
    const float* wco = w + (size_t)co * Cin * 9;
    for (int ci = c0; ci < c1; ++ci) {
        const float* inp = in + (size_t)ci * H * W;
        const float* wp = wco + (size_t)ci * 9;
        #pragma unroll
        for (int ky = 0; ky < 3; ++ky) {
            int iy = y + ky - 1;
            if (iy < 0 || iy >= H) continue;
            const float* rowp = inp + iy * W;
            #pragma unroll
            for (int kx = 0; kx < 3; ++kx) {
                int ix = x + kx - 1;
                if (ix < 0 || ix >= W) continue;
                acc += rowp[ix] * wp[ky * 3 + kx];
            }
        }
    }
    sm[t] = acc;
    __syncthreads();
    float* res = sm + P * CC;
    if (chunk == 0) {
        float tot = bias[co];
        for (int cc2 = 0; cc2 < CC; ++cc2) tot += sm[pix + cc2 * P];
        res[pix] = tot > 0.f ? tot : 0.f;
    }
    __syncthreads();
    int pH = (tileH - pk) / ps + 1, pW = (tileW - pk) / ps + 1;
    if (t < pH * pW) {
        int py = t / pW, px = t % pW;
        float best = -INFINITY;
        for (int dy = 0; dy < pk; ++dy)
            for (int dx = 0; dx < pk; ++dx) {
                float v = res[(py * ps + dy) * tileW + (px * ps + dx)];
                best = v > best ? v : best;
            }
        out[((size_t)co * PHf + (ty0 / ps + py)) * PWf + (tx0 / ps + px)] = best;
    }
}

// ---------------- 7) head ----------------
__global__ void head_kernel(const float* __restrict__ feat,
                            const float* __restrict__ dnn_w, const float* __restrict__ dnn_b,
                            const float* __restrict__ out_w, const float* __restrict__ out_b,
                            float* __restrict__ out)
{
    __shared__ float y[128];
    __shared__ float logits[5];
    int j = threadIdx.x;
    float acc = dnn_b[j];
    for (int k = 0; k < 128; ++k) acc += feat[k] * dnn_w[j * 128 + k];
    y[j] = acc > 0.f ? acc : 0.f;
    __syncthreads();
    if (j < 5) {
        float a = out_b[j];
        for (int k = 0; k < 128; ++k) a += y[k] * out_w[j * 128 + k];
        logits[j] = a;
    }
    __syncthreads();
    if (j == 0) {
        float m = logits[0];
        for (int l = 1; l < 5; ++l) m = fmaxf(m, logits[l]);
        float s = 0.f;
        for (int l = 0; l < 5; ++l) s += expf(logits[l] - m);
        float lse = logf(s);
        for (int l = 0; l < 5; ++l) out[l] = logits[l] - m - lse;
    }
}

extern "C" void kernel_launch(void* const* d_in, const int* in_sizes, int n_in,
                              void* d_out, int out_size, void* d_ws, size_t ws_size,
                              hipStream_t stream)
{
    const int*   x1     = (const int*)d_in[0];
    const int*   x2     = (const int*)d_in[1];
    const float* emb    = (const float*)d_in[2];
    const float* w_ih_f = (const float*)d_in[3];
    const float* w_hh_f = (const float*)d_in[4];
    const float* b_f    = (const float*)d_in[5];
    const float* w_ih_b = (const float*)d_in[6];
    const float* w_hh_b = (const float*)d_in[7];
    const float* b_b    = (const float*)d_in[8];
    const float* c1_w   = (const float*)d_in[9];
    const float* c1_b   = (const float*)d_in[10];
    const float* c2_w   = (const float*)d_in[11];
    const float* c2_b   = (const float*)d_in[12];
    const float* c3_w   = (const float*)d_in[13];
    const float* c3_b   = (const float*)d_in[14];
    const float* c4_w   = (const float*)d_in[15];
    const float* c4_b   = (const float*)d_in[16];
    const float* c5_w   = (const float*)d_in[17];
    const float* c5_b   = (const float*)d_in[18];
    const float* dnn_w  = (const float*)d_in[19];
    const float* dnn_b  = (const float*)d_in[20];
    const float* out_w  = (const float*)d_in[21];
    const float* out_b  = (const float*)d_in[22];

    float* ws    = (float*)d_ws;
    float* xW    = ws + OFF_XW;
    float* hsb   = ws + OFF_HS;
    float* sc    = ws + OFF_SC;
    float* bufA  = ws + OFF_BUFA;
    float* bufB  = ws + OFF_BUFB;
    float* wihT  = ws + OFF_WIHT;
    unsigned char* sel = (unsigned char*)(ws + OFF_SEL);
    float* outp  = (float*)d_out;

    transpose_wih_kernel<<<dim3(32, 10, 2), dim3(32, 32), 0, stream>>>(w_ih_f, w_ih_b, wihT);
    embed_xw_kernel<<<192, 512, 0, stream>>>(x1, x2, emb, wihT, b_f, b_b, xW);
    lstm_kernel<<<4, 256, 0, stream>>>(xW, w_hh_f, w_hh_b, hsb);
    sim_kernel<<<2304, 64, 0, stream>>>(hsb, sc);
    greedy_kernel<<<2, 64, 0, stream>>>(sc, sel);

    // conv stack: 13x48x48 ->128x24x24 ->164x12x12 ->192x6x6 ->192x3x3 ->128
    conv1_pool_kernel<<<128 * 9, 256, 0, stream>>>(sc, sel, c1_w, c1_b, bufA);
    conv_cs_kernel<<<dim3(164, 2, 2), 576, (576 + 144) * 4, stream>>>(
        bufA, c2_w, c2_b, bufB, 128, 24, 24, 12, 12, 32, 4, 2, 2, 12, 12);
    conv_cs_kernel<<<dim3(192, 1, 1), 576, (576 + 144) * 4, stream>>>(
        bufB, c3_w, c3_b, bufA, 164, 12, 12, 12, 12, 41, 4, 2, 2, 6, 6);
    conv_cs_kernel<<<dim3(192, 1, 1), 576, (576 + 36) * 4, stream>>>(
        bufA, c4_w, c4_b, bufB, 192, 6, 6, 6, 6, 12, 16, 2, 2, 3, 3);
    conv_cs_kernel<<<dim3(128, 1, 1), 576, (576 + 9) * 4, stream>>>(
        bufB, c5_w, c5_b, bufA, 192, 3, 3, 3, 3, 3, 64, 3, 1, 1, 1);

    head_kernel<<<1, 128, 0, stream>>>(bufA, dnn_w, dnn_b, out_w, out_b, outp);
}